// Round 1
// baseline (3190.307 us; speedup 1.0000x reference)
//
#include <hip/hip_runtime.h>

#define T_TOK 8192
#define HD 2048
#define ID 5632
#define NE 8

typedef __bf16 bf16x8 __attribute__((ext_vector_type(8)));
typedef float f32x4 __attribute__((ext_vector_type(4)));

__device__ __forceinline__ unsigned short f2bf(float f) {
    unsigned int u = __builtin_bit_cast(unsigned int, f);
    u += 0x7fffu + ((u >> 16) & 1u);
    return (unsigned short)(u >> 16);
}

__device__ __forceinline__ void gl_lds16(void* lds, const void* g) {
    __builtin_amdgcn_global_load_lds(
        (const __attribute__((address_space(1))) unsigned int*)g,
        (__attribute__((address_space(3))) unsigned int*)lds,
        16, 0, 0);
}

// ---------------- zero out + counts ----------------
__global__ void zero_out_kernel(float4* __restrict__ out4, int* __restrict__ counts) {
    int gid = blockIdx.x * 256 + threadIdx.x;
    out4[gid] = make_float4(0.f, 0.f, 0.f, 0.f);
    if (blockIdx.x == 0 && threadIdx.x < NE) counts[threadIdx.x] = 0;
}

// ---------------- router: logits -> softmax -> top2 -> lists ----------------
__global__ __launch_bounds__(256)
void router_kernel(const float* __restrict__ x, const float* __restrict__ gw,
                   int* __restrict__ counts, int* __restrict__ lists,
                   float* __restrict__ wts) {
    const int t = blockIdx.x;
    const int tid = threadIdx.x;
    const float* xr = x + (size_t)t * HD;
    float acc[NE];
#pragma unroll
    for (int e = 0; e < NE; ++e) acc[e] = 0.f;
    for (int i = tid; i < HD; i += 256) {
        float xv = xr[i];
#pragma unroll
        for (int e = 0; e < NE; ++e) acc[e] += xv * gw[e * HD + i];
    }
#pragma unroll
    for (int e = 0; e < NE; ++e)
        for (int off = 32; off > 0; off >>= 1)
            acc[e] += __shfl_down(acc[e], off);
    __shared__ float part[4][NE];
    const int wave = tid >> 6, lane = tid & 63;
    if (lane == 0) {
#pragma unroll
        for (int e = 0; e < NE; ++e) part[wave][e] = acc[e];
    }
    __syncthreads();
    if (tid == 0) {
        float l[NE];
#pragma unroll
        for (int e = 0; e < NE; ++e) l[e] = part[0][e] + part[1][e] + part[2][e] + part[3][e];
        int i1 = 0;
        for (int e = 1; e < NE; ++e) if (l[e] > l[i1]) i1 = e;
        int i2 = (i1 == 0) ? 1 : 0;
        for (int e = 0; e < NE; ++e) if (e != i1 && l[e] > l[i2]) i2 = e;
        // top-2 softmax renormalized == 2-way softmax of the two top logits
        float e2 = __expf(l[i2] - l[i1]);
        float inv = 1.f / (1.f + e2);
        int p1 = atomicAdd(&counts[i1], 1);
        lists[i1 * T_TOK + p1] = t; wts[i1 * T_TOK + p1] = inv;
        int p2 = atomicAdd(&counts[i2], 1);
        lists[i2 * T_TOK + p2] = t; wts[i2 * T_TOK + p2] = e2 * inv;
    }
}

// ---------------- cast x fp32 -> bf16 ----------------
__global__ void cast_x_kernel(const float4* __restrict__ x4, ushort4* __restrict__ xb4) {
    int gid = blockIdx.x * 256 + threadIdx.x;
    float4 v = x4[gid];
    xb4[gid] = make_ushort4(f2bf(v.x), f2bf(v.y), f2bf(v.z), f2bf(v.w));
}

// ---------------- per-expert weight fp32 -> bf16 (3 matrices, same size) ----------------
__global__ void conv_w_kernel(const float* __restrict__ a, const float* __restrict__ b,
                              const float* __restrict__ c,
                              unsigned short* __restrict__ da, unsigned short* __restrict__ db,
                              unsigned short* __restrict__ dc) {
    int gid = blockIdx.x * 256 + threadIdx.x;
    const float* s; unsigned short* d;
    if (blockIdx.y == 0)      { s = a; d = da; }
    else if (blockIdx.y == 1) { s = b; d = db; }
    else                      { s = c; d = dc; }
    float4 v = ((const float4*)s)[gid];
    ((ushort4*)d)[gid] = make_ushort4(f2bf(v.x), f2bf(v.y), f2bf(v.z), f2bf(v.w));
}

// ---------------- GEMM1: h[pos,i] = silu(x@wg^T) * (x@wu^T), gathered rows ----------------
// 128x128 tile, BK=32, 4 waves in 2x2, each wave 4x4 of 16x16x32 MFMA, dual B.
__global__ __launch_bounds__(256, 2)
void gemm1_kernel(const unsigned short* __restrict__ xbf,
                  const unsigned short* __restrict__ wg,
                  const unsigned short* __restrict__ wu,
                  unsigned short* __restrict__ hbuf,
                  const int* __restrict__ count_p,
                  const int* __restrict__ list) {
    const int n_e = *count_p;
    const int m0 = blockIdx.y * 128;
    if (m0 >= n_e) return;
    const int n0 = blockIdx.x * 128;

    __shared__ unsigned short sA[128 * 32];
    __shared__ unsigned short sBg[128 * 32];
    __shared__ unsigned short sBu[128 * 32];

    const int tid = threadIdx.x;
    const int lane = tid & 63;
    const int wave = tid >> 6;

    const unsigned short* gA[2];
    const unsigned short* gBg[2];
    const unsigned short* gBu[2];
#pragma unroll
    for (int j = 0; j < 2; ++j) {
        const int off = wave * 2048 + j * 1024 + lane * 16; // byte offset in 8KB tile
        const int r = off >> 6;                             // tile row
        const int ce = (off & 63) >> 1;                     // element col in k
        int pos = m0 + r;
        if (pos > n_e - 1) pos = n_e - 1;                   // clamp pad rows (garbage ok, masked later)
        const int tok = list[pos];
        gA[j]  = xbf + (size_t)tok * HD + ce;
        gBg[j] = wg + (size_t)(n0 + r) * HD + ce;
        gBu[j] = wu + (size_t)(n0 + r) * HD + ce;
    }

    f32x4 accg[4][4], accu[4][4];
    const f32x4 fzero = {0.f, 0.f, 0.f, 0.f};
#pragma unroll
    for (int i = 0; i < 4; ++i)
#pragma unroll
        for (int j = 0; j < 4; ++j) { accg[i][j] = fzero; accu[i][j] = fzero; }

    const int mrow = ((wave >> 1) * 64 + (lane & 15)) * 32; // element offset of A frag row
    const int nrow = ((wave & 1) * 64 + (lane & 15)) * 32;
    const int ko = (lane >> 4) * 8;

    for (int kt = 0; kt < HD / 32; ++kt) {
        const int kofs = kt * 32;
        __syncthreads();
#pragma unroll
        for (int j = 0; j < 2; ++j) {
            const int seg = wave * 1024 + j * 512;          // wave-uniform LDS base (elements)
            gl_lds16(sA + seg,  gA[j] + kofs);
            gl_lds16(sBg + seg, gBg[j] + kofs);
            gl_lds16(sBu + seg, gBu[j] + kofs);
        }
        __syncthreads();
        bf16x8 av[4], bgv[4], buv[4];
#pragma unroll
        for (int i = 0; i < 4; ++i) av[i] = *(const bf16x8*)(sA + mrow + i * 512 + ko);
#pragma unroll
        for (int j = 0; j < 4; ++j) {
            bgv[j] = *(const bf16x8*)(sBg + nrow + j * 512 + ko);
            buv[j] = *(const bf16x8*)(sBu + nrow + j * 512 + ko);
        }
#pragma unroll
        for (int i = 0; i < 4; ++i)
#pragma unroll
            for (int j = 0; j < 4; ++j) {
                accg[i][j] = __builtin_amdgcn_mfma_f32_16x16x32_bf16(av[i], bgv[j], accg[i][j], 0, 0, 0);
                accu[i][j] = __builtin_amdgcn_mfma_f32_16x16x32_bf16(av[i], buv[j], accu[i][j], 0, 0, 0);
            }
    }

    // epilogue: silu(g)*u -> bf16 h, C/D layout col=lane&15, row=(lane>>4)*4+r
    const int qr = (lane >> 4) << 2;
    const int qc = lane & 15;
    const int rb = m0 + (wave >> 1) * 64 + qr;
    const int cb = n0 + (wave & 1) * 64 + qc;
#pragma unroll
    for (int i = 0; i < 4; ++i)
#pragma unroll
        for (int r = 0; r < 4; ++r) {
            const size_t rowoff = (size_t)(rb + i * 16 + r) * ID;
#pragma unroll
            for (int j = 0; j < 4; ++j) {
                float g = accg[i][j][r];
                float u = accu[i][j][r];
                float s = g / (1.f + __expf(-g));
                hbuf[rowoff + cb + j * 16] = f2bf(s * u);
            }
        }
}

// ---------------- GEMM2: out[tok,:] += (h @ wd^T) * wt  (BM=64, BN=128) ----------------
__global__ __launch_bounds__(256, 3)
void gemm2_kernel(const unsigned short* __restrict__ hbuf,
                  const unsigned short* __restrict__ wd,
                  float* __restrict__ out,
                  const int* __restrict__ count_p,
                  const int* __restrict__ list,
                  const float* __restrict__ wts) {
    const int n_e = *count_p;
    const int m0 = blockIdx.y * 64;
    if (m0 >= n_e) return;
    const int n0 = blockIdx.x * 128;

    __shared__ unsigned short sA[64 * 32];
    __shared__ unsigned short sB[128 * 32];

    const int tid = threadIdx.x;
    const int lane = tid & 63;
    const int wave = tid >> 6;

    const int offA = wave * 1024 + lane * 16;
    const int rA = offA >> 6;
    const int ceA = (offA & 63) >> 1;
    const unsigned short* gA = hbuf + (size_t)(m0 + rA) * ID + ceA;
    const int segA = wave * 512;

    const unsigned short* gB[2];
#pragma unroll
    for (int j = 0; j < 2; ++j) {
        const int off = wave * 2048 + j * 1024 + lane * 16;
        const int r = off >> 6;
        const int ce = (off & 63) >> 1;
        gB[j] = wd + (size_t)(n0 + r) * ID + ce;
    }

    f32x4 acc[4][2];
    const f32x4 fzero = {0.f, 0.f, 0.f, 0.f};
#pragma unroll
    for (int i = 0; i < 4; ++i) { acc[i][0] = fzero; acc[i][1] = fzero; }

    const int mrow = (lane & 15) * 32;
    const int nrow = (wave * 32 + (lane & 15)) * 32;
    const int ko = (lane >> 4) * 8;

    for (int kt = 0; kt < ID / 32; ++kt) {
        const int kofs = kt * 32;
        __syncthreads();
        gl_lds16(sA + segA, gA + kofs);
#pragma unroll
        for (int j = 0; j < 2; ++j)
            gl_lds16(sB + wave * 1024 + j * 512, gB[j] + kofs);
        __syncthreads();
        bf16x8 av[4], bv[2];
#pragma unroll
        for (int i = 0; i < 4; ++i) av[i] = *(const bf16x8*)(sA + mrow + i * 512 + ko);
#pragma unroll
        for (int j = 0; j < 2; ++j) bv[j] = *(const bf16x8*)(sB + nrow + j * 512 + ko);
#pragma unroll
        for (int i = 0; i < 4; ++i)
#pragma unroll
            for (int j = 0; j < 2; ++j)
                acc[i][j] = __builtin_amdgcn_mfma_f32_16x16x32_bf16(av[i], bv[j], acc[i][j], 0, 0, 0);
    }

    const int qr = (lane >> 4) << 2;
    const int qc = lane & 15;
    const int cb = n0 + wave * 32 + qc;
#pragma unroll
    for (int i = 0; i < 4; ++i)
#pragma unroll
        for (int r = 0; r < 4; ++r) {
            const int pos = m0 + i * 16 + qr + r;
            if (pos < n_e) {                       // mask pad rows
                const int tok = list[pos];
                const float w = wts[pos];
                float* orow = out + (size_t)tok * HD + cb;
#pragma unroll
                for (int j = 0; j < 2; ++j)
                    orow[j * 16] += acc[i][j][r] * w;   // safe RMW: token unique per expert, experts serialized
            }
        }
}

// ---------------- launch ----------------
extern "C" void kernel_launch(void* const* d_in, const int* in_sizes, int n_in,
                              void* d_out, int out_size, void* d_ws, size_t ws_size,
                              hipStream_t stream) {
    const float* x      = (const float*)d_in[0];
    const float* gw     = (const float*)d_in[1];
    const float* w_gate = (const float*)d_in[2];
    const float* w_up   = (const float*)d_in[3];
    const float* w_down = (const float*)d_in[4];
    float* out = (float*)d_out;

    char* ws = (char*)d_ws;
    int*   counts = (int*)ws;                              // 8 ints
    int*   lists  = (int*)(ws + 256);                      // 8*8192 ints
    float* wts    = (float*)(ws + 256 + NE * T_TOK * 4);   // 8*8192 floats
    unsigned short* xbf = (unsigned short*)(ws + 256 + NE * T_TOK * 8);
    unsigned short* wgb = xbf + (size_t)T_TOK * HD;
    unsigned short* wub = wgb + (size_t)ID * HD;
    unsigned short* wdb = wub + (size_t)ID * HD;
    unsigned short* hbuf = wdb + (size_t)ID * HD;          // [T_TOK, ID] bf16
    // total ws use ~195.6 MB

    zero_out_kernel<<<16384, 256, 0, stream>>>((float4*)out, counts);   // 16.78M floats
    router_kernel<<<T_TOK, 256, 0, stream>>>(x, gw, counts, lists, wts);
    cast_x_kernel<<<16384, 256, 0, stream>>>((const float4*)x, (ushort4*)xbf);

    const size_t WSZ = (size_t)ID * HD;                    // 11,534,336 elems per matrix
    for (int e = 0; e < NE; ++e) {
        conv_w_kernel<<<dim3(WSZ / 1024, 3), 256, 0, stream>>>(
            w_gate + e * WSZ, w_up + e * WSZ, w_down + e * WSZ, wgb, wub, wdb);
        gemm1_kernel<<<dim3(ID / 128, T_TOK / 128), 256, 0, stream>>>(
            xbf, wgb, wub, hbuf, counts + e, lists + e * T_TOK);
        gemm2_kernel<<<dim3(HD / 128, T_TOK / 64), 256, 0, stream>>>(
            hbuf, wdb, out, counts + e, lists + e * T_TOK, wts + e * T_TOK);
    }
}